// Round 7
// baseline (342.874 us; speedup 1.0000x reference)
//
#include <hip/hip_runtime.h>
#include <hip/hip_bf16.h>
#include <stdint.h>

#define KDIM 4096
#define NDIM 4096
#define MDIM 4096
#define BM 256
#define BN 256
#define BK 64

typedef __attribute__((ext_vector_type(8))) short bf16x8;
typedef __attribute__((ext_vector_type(4))) float f32x4;

// ---------- helpers ----------

__device__ __forceinline__ unsigned short bf16bits(float f) {
    union { float f; uint32_t u; } c; c.f = f;
    uint32_t u = c.u;
    uint32_t r = (u + 0x7fffu + ((u >> 16) & 1u)) >> 16;   // RNE
    return (unsigned short)r;
}

// Faithful FP4 E2M1 quant-dequant (matches reference float math).
__device__ __forceinline__ float fp4qd(float x) {
    float a = fabsf(x);
    if (a == 0.0f) return 0.0f;
    float e = floorf(log2f(a));
    float val;
    if (e < 0.0f) {                       // subnormal path
        float mant = fminf(fmaxf(rintf(a * 2.0f), 0.0f), 1.0f);
        val = mant * 0.5f;
    } else {
        float ec = fminf(e, 2.0f);
        float p  = exp2f(ec);             // exact: 1,2,4
        float mant = fminf(fmaxf(rintf((a / p - 1.0f) * 2.0f), 0.0f), 1.0f);
        val = (1.0f + 0.5f * mant) * p;
    }
    return (x < 0.0f) ? -val : val;
}

__device__ __forceinline__ void gld16(void* lds, const void* g) {
    __builtin_amdgcn_global_load_lds(
        (const __attribute__((address_space(1))) unsigned int*)g,
        (__attribute__((address_space(3))) unsigned int*)lds,
        16, 0, 0);
}

// ---------- fused prep: x f32->bf16  +  weight fp4-quant-dequant->bf16 ----
__global__ __launch_bounds__(256) void prep_kernel(const float* __restrict__ X,
                                                   const float* __restrict__ W,
                                                   unsigned short* __restrict__ Xb,
                                                   unsigned short* __restrict__ Wq) {
    int bid = blockIdx.x;
    int tid = threadIdx.x;
    if (bid < 16384) {
        size_t i = ((size_t)bid * 256 + tid) * 4;
        float4 v = *(const float4*)(X + i);
        ushort4 o;
        o.x = bf16bits(v.x); o.y = bf16bits(v.y);
        o.z = bf16bits(v.z); o.w = bf16bits(v.w);
        *(ushort4*)(Xb + i) = o;
    } else {
        size_t base = ((size_t)(bid - 16384) * 256 + tid) * 4;
        float4 v = *(const float4*)(W + base);
        float am = fmaxf(fmaxf(fabsf(v.x), fabsf(v.y)),
                         fmaxf(fabsf(v.z), fabsf(v.w)));
        #pragma unroll
        for (int s = 16; s; s >>= 1) am = fmaxf(am, __shfl_xor(am, s));  // 32-lane group
        float scale = (am == 0.0f) ? 1.0f : am / 6.0f;
        ushort4 o;
        o.x = bf16bits(fp4qd(v.x / scale) * scale);
        o.y = bf16bits(fp4qd(v.y / scale) * scale);
        o.z = bf16bits(fp4qd(v.z / scale) * scale);
        o.w = bf16bits(fp4qd(v.w / scale) * scale);
        *(ushort4*)(Wq + base) = o;
    }
}

// ---------- GEMM: 256x256-tile 8-phase, 16x16x32 MFMA (R6 skeleton) -------
// template<V>: 0 = full/correct (dispatched LAST, owns d_out)
//              1 = ABLATION: no in-loop ds_reads (frozen prologue fragments)
//              2 = ABLATION: no in-loop staging / vmcnt
// V1/V2 produce wrong data; V0 fully overwrites d_out afterwards.

#define BAR()    __builtin_amdgcn_s_barrier()
#define LGKM0()  asm volatile("s_waitcnt lgkmcnt(0)" ::: "memory")
#define VM4()    asm volatile("s_waitcnt vmcnt(4)" ::: "memory")
#define SCH0()   __builtin_amdgcn_sched_barrier(0)
#define PRIO(x)  __builtin_amdgcn_s_setprio(x)

template<int V>
__global__ __launch_bounds__(512, 2) void gemm256(const unsigned short* __restrict__ A,
                                                  const unsigned short* __restrict__ B,
                                                  const float* __restrict__ bias,
                                                  float* __restrict__ C) {
    __shared__ __attribute__((aligned(16))) char smem[2][2][2][16384];
    char* sm = (char*)&smem[0][0][0][0];

    const int t = threadIdx.x;
    const int l = t & 63;
    const int w = __builtin_amdgcn_readfirstlane(t >> 6);  // 0..7
    const int wm = w >> 2;        // 0..1  (M half)
    const int wn = w & 3;         // 0..3  (N quarter)

    // bijective XCD swizzle (256 blocks, 8 XCDs)
    int bid = blockIdx.x;
    int swz = (bid & 7) * 32 + (bid >> 3);
    int brow = (swz >> 4) * BM;
    int bcol = (swz & 15) * BN;

    // ---- staging addresses (pre-swizzled global source, linear LDS dest) ----
    const int lr8  = l >> 3;                 // row in 8-row slab
    const int slot = l & 7;
    const int scol = (slot ^ lr8) << 3;      // swizzled source col (elements)
    const unsigned short* pA = A + (size_t)(brow + w * 8 + lr8) * KDIM + scol;
    const unsigned short* pB = B + (size_t)(bcol + w * 8 + lr8) * KDIM + scol;

#define STAGE(b, op, h, kt) do {                                               \
    const unsigned short* _s = ((op) ? pB : pA)                                \
        + (size_t)(h) * 128 * KDIM + (size_t)(kt) * BK;                        \
    gld16(sm + (b) * 65536 + (op) * 32768 + (h) * 16384 + w * 1024, _s);       \
    gld16(sm + (b) * 65536 + (op) * 32768 + (h) * 16384 + 8192 + w * 1024,     \
          _s + (size_t)64 * KDIM);                                             \
} while (0)

    // ---- fragment read addressing ----
    const int fr  = l & 15;
    const int fq  = l >> 4;
    const int kx0 = ((fq    ) ^ (fr & 7)) << 4;   // ks=0 swizzled chunk byte
    const int kx1 = ((fq + 4) ^ (fr & 7)) << 4;   // ks=1
    const int frA = fr * 128;

#define RD_A(b, mh) do {                                                        \
    const char* _p = sm + (b) * 65536 + wm * 16384 + (mh) * 8192 + frA;         \
    _Pragma("unroll")                                                           \
    for (int m = 0; m < 4; ++m) {                                               \
        av[m][0] = *(const bf16x8*)(_p + m * 2048 + kx0);                       \
        av[m][1] = *(const bf16x8*)(_p + m * 2048 + kx1);                       \
    }                                                                           \
} while (0)

#define RD_B(b, nh, arr) do {                                                   \
    const char* _p = sm + (b) * 65536 + 32768 + wn * 8192 + (nh) * 4096 + frA;  \
    _Pragma("unroll")                                                           \
    for (int n = 0; n < 2; ++n) {                                               \
        arr[n][0] = *(const bf16x8*)(_p + n * 2048 + kx0);                      \
        arr[n][1] = *(const bf16x8*)(_p + n * 2048 + kx1);                      \
    }                                                                           \
} while (0)

#define MM(mh, nh, B_)                                                          \
    _Pragma("unroll")                                                           \
    for (int m = 0; m < 4; ++m)                                                 \
        _Pragma("unroll")                                                       \
        for (int n = 0; n < 2; ++n)                                             \
            _Pragma("unroll")                                                   \
            for (int ks = 0; ks < 2; ++ks)                                      \
                acc[(mh) * 4 + m][(nh) * 2 + n] =                               \
                    __builtin_amdgcn_mfma_f32_16x16x32_bf16(                    \
                        av[m][ks], B_[n][ks], acc[(mh) * 4 + m][(nh) * 2 + n],  \
                        0, 0, 0);

    f32x4 acc[8][4];
    #pragma unroll
    for (int m = 0; m < 8; ++m)
        #pragma unroll
        for (int n = 0; n < 4; ++n)
            acc[m][n] = f32x4{0.f, 0.f, 0.f, 0.f};

    bf16x8 av[4][2], bvA[2][2], bvB[2][2];

    // ---- prologue: tile0 full (8 gld) + t1.B0 + t1.A0 (4 gld) ----
    STAGE(0, 0, 0, 0); STAGE(0, 0, 1, 0); STAGE(0, 1, 0, 0); STAGE(0, 1, 1, 0);
    STAGE(1, 1, 0, 1); STAGE(1, 0, 0, 1);
    VM4();            // tile0 landed; t1.B0/A0 in flight
    BAR();
    RD_B(0, 0, bvA);  // pre-read t0.B0 (consumed P1, P4)
    if constexpr (V == 1) {   // freeze all fragment regs for the ablation
        RD_A(0, 0); RD_B(0, 1, bvB);
    }
    SCH0();

    // ---- main loop: iter computes K-tiles 2it (buf0) and 2it+1 (buf1) ----
    for (int it = 0; it < 32; ++it) {
        const int k1 = 2 * it + 1;
        const int k2 = (2 * it + 2) & 63;   // wrap on last iter (never read)
        const int k3 = (2 * it + 3) & 63;

        // P1: read buf0 A-mh0 (8) ; stage t1.A1
        if constexpr (V != 1) { RD_A(0, 0); }
        if constexpr (V != 2) { STAGE(1, 0, 1, k1); }
        BAR(); LGKM0(); SCH0(); PRIO(1); MM(0, 0, bvA); PRIO(0); BAR(); SCH0();
        // P2: read buf0 B-nh1 (4) ; stage t1.B1
        if constexpr (V != 1) { RD_B(0, 1, bvB); }
        if constexpr (V != 2) { STAGE(1, 1, 1, k1); }
        BAR(); LGKM0(); SCH0(); PRIO(1); MM(0, 1, bvB); PRIO(0); BAR(); SCH0();
        // P3: read buf0 A-mh1 (8) ; stage t2.B0
        if constexpr (V != 1) { RD_A(0, 1); }
        if constexpr (V != 2) { STAGE(0, 1, 0, k2); }
        BAR(); LGKM0(); SCH0(); PRIO(1); MM(1, 1, bvB); PRIO(0); BAR(); SCH0();
        // P4: stage t2.A0 ; VM4 -> buf1 landed ; tail-read buf1.B0 (4)
        if constexpr (V != 2) { STAGE(0, 0, 0, k2); }
        BAR(); SCH0(); PRIO(1); MM(1, 0, bvA); PRIO(0);
        if constexpr (V != 2) { VM4(); }
        if constexpr (V != 1) { RD_B(1, 0, bvA); }
        BAR(); SCH0();

        // P5: read buf1 A-mh0 (8) ; stage t2.A1
        if constexpr (V != 1) { RD_A(1, 0); }
        if constexpr (V != 2) { STAGE(0, 0, 1, k2); }
        BAR(); LGKM0(); SCH0(); PRIO(1); MM(0, 0, bvA); PRIO(0); BAR(); SCH0();
        // P6: read buf1 B-nh1 (4) ; stage t2.B1
        if constexpr (V != 1) { RD_B(1, 1, bvB); }
        if constexpr (V != 2) { STAGE(0, 1, 1, k2); }
        BAR(); LGKM0(); SCH0(); PRIO(1); MM(0, 1, bvB); PRIO(0); BAR(); SCH0();
        // P7: read buf1 A-mh1 (8) ; stage t3.B0
        if constexpr (V != 1) { RD_A(1, 1); }
        if constexpr (V != 2) { STAGE(1, 1, 0, k3); }
        BAR(); LGKM0(); SCH0(); PRIO(1); MM(1, 1, bvB); PRIO(0); BAR(); SCH0();
        // P8: stage t3.A0 ; VM4 -> buf0 (t2) landed ; tail-read buf0.B0 (4)
        if constexpr (V != 2) { STAGE(1, 0, 0, k3); }
        BAR(); SCH0(); PRIO(1); MM(1, 0, bvA); PRIO(0);
        if constexpr (V != 2) { VM4(); }
        if constexpr (V != 1) { RD_B(0, 0, bvA); }
        BAR(); SCH0();
    }

    // ---- epilogue: C[row][col] = acc + bias[col] ----
    float bb[4];
    #pragma unroll
    for (int n = 0; n < 4; ++n) bb[n] = bias[bcol + wn * 64 + n * 16 + fr];
    #pragma unroll
    for (int mi = 0; mi < 8; ++mi) {
        #pragma unroll
        for (int q = 0; q < 4; ++q) {
            int row = brow + wm * 128 + mi * 16 + fq * 4 + q;
            float* crow = C + (size_t)row * NDIM + bcol + wn * 64;
            #pragma unroll
            for (int n = 0; n < 4; ++n)
                crow[n * 16 + fr] = acc[mi][n][q] + bb[n];
        }
    }
}

// ---------- launch ----------
extern "C" void kernel_launch(void* const* d_in, const int* in_sizes, int n_in,
                              void* d_out, int out_size, void* d_ws, size_t ws_size,
                              hipStream_t stream) {
    const float* x = (const float*)d_in[0];
    const float* w = (const float*)d_in[1];
    const float* b = (const float*)d_in[2];
    float* out = (float*)d_out;

    unsigned short* xb = (unsigned short*)d_ws;                         // 32 MB
    unsigned short* wq = xb + (size_t)NDIM * KDIM;                      // 32 MB

    prep_kernel<<<32768, 256, 0, stream>>>(x, w, xb, wq);
    // Diagnostic ablations (write garbage, fully overwritten by V0 below):
    gemm256<1><<<(MDIM / BM) * (NDIM / BN), 512, 0, stream>>>(xb, wq, b, out);
    gemm256<2><<<(MDIM / BM) * (NDIM / BN), 512, 0, stream>>>(xb, wq, b, out);
    // Control / correct output (last):
    gemm256<0><<<(MDIM / BM) * (NDIM / BN), 512, 0, stream>>>(xb, wq, b, out);
}

// Round 8
// 220.004 us; speedup vs baseline: 1.5585x; 1.5585x over previous
//
#include <hip/hip_runtime.h>
#include <hip/hip_bf16.h>
#include <stdint.h>

#define KDIM 4096
#define NDIM 4096
#define MDIM 4096
#define BM 256
#define BN 256
#define BK 64

typedef __attribute__((ext_vector_type(8))) short bf16x8;
typedef __attribute__((ext_vector_type(4))) float f32x4;

// ---------- helpers ----------

__device__ __forceinline__ unsigned short bf16bits(float f) {
    union { float f; uint32_t u; } c; c.f = f;
    uint32_t u = c.u;
    uint32_t r = (u + 0x7fffu + ((u >> 16) & 1u)) >> 16;   // RNE
    return (unsigned short)r;
}

// Faithful FP4 E2M1 quant-dequant (matches reference float math).
__device__ __forceinline__ float fp4qd(float x) {
    float a = fabsf(x);
    if (a == 0.0f) return 0.0f;
    float e = floorf(log2f(a));
    float val;
    if (e < 0.0f) {                       // subnormal path
        float mant = fminf(fmaxf(rintf(a * 2.0f), 0.0f), 1.0f);
        val = mant * 0.5f;
    } else {
        float ec = fminf(e, 2.0f);
        float p  = exp2f(ec);             // exact: 1,2,4
        float mant = fminf(fmaxf(rintf((a / p - 1.0f) * 2.0f), 0.0f), 1.0f);
        val = (1.0f + 0.5f * mant) * p;
    }
    return (x < 0.0f) ? -val : val;
}

__device__ __forceinline__ void gld16(void* lds, const void* g) {
    __builtin_amdgcn_global_load_lds(
        (const __attribute__((address_space(1))) unsigned int*)g,
        (__attribute__((address_space(3))) unsigned int*)lds,
        16, 0, 0);
}

// ---------- fused prep: x f32->bf16  +  weight fp4-quant-dequant->bf16 ----
__global__ __launch_bounds__(256) void prep_kernel(const float* __restrict__ X,
                                                   const float* __restrict__ W,
                                                   unsigned short* __restrict__ Xb,
                                                   unsigned short* __restrict__ Wq) {
    int bid = blockIdx.x;
    int tid = threadIdx.x;
    if (bid < 16384) {
        size_t i = ((size_t)bid * 256 + tid) * 4;
        float4 v = *(const float4*)(X + i);
        ushort4 o;
        o.x = bf16bits(v.x); o.y = bf16bits(v.y);
        o.z = bf16bits(v.z); o.w = bf16bits(v.w);
        *(ushort4*)(Xb + i) = o;
    } else {
        size_t base = ((size_t)(bid - 16384) * 256 + tid) * 4;
        float4 v = *(const float4*)(W + base);
        float am = fmaxf(fmaxf(fabsf(v.x), fabsf(v.y)),
                         fmaxf(fabsf(v.z), fabsf(v.w)));
        #pragma unroll
        for (int s = 16; s; s >>= 1) am = fmaxf(am, __shfl_xor(am, s));  // 32-lane group
        float scale = (am == 0.0f) ? 1.0f : am / 6.0f;
        ushort4 o;
        o.x = bf16bits(fp4qd(v.x / scale) * scale);
        o.y = bf16bits(fp4qd(v.y / scale) * scale);
        o.z = bf16bits(fp4qd(v.z / scale) * scale);
        o.w = bf16bits(fp4qd(v.w / scale) * scale);
        *(ushort4*)(Wq + base) = o;
    }
}

// ---------- GEMM: 256x256 tile, A-in-LDS / B-in-registers, 1 barrier/K-tile
// C = A @ B^T + bias. 8 waves (2M x 4N), per-wave 128x64 out, acc[8][4].
// A: LDS double-buffer [2][32KB] (chunk-XOR swizzled, conflict-free b128).
// B: per-wave register fragments, global_load_dwordx4 direct (wm-partner
//    wave loads identical addresses -> L1 hit; no LDS writes/reads for B).
// Per K-tile: VM(0)+BAR (drain loads issued one full tile earlier, ~2600cy
// slack), 16 A-ds_reads, 8 B-glb loads (T+1), 4 A-gld16 stages (T+1),
// two 32-MFMA clusters with lgkm(0) between. Waves desync inside the
// barrier-free tile -> h1-read service overlaps other waves' MFMA.

#define BAR()    __builtin_amdgcn_s_barrier()
#define LGKM0()  asm volatile("s_waitcnt lgkmcnt(0)" ::: "memory")
#define VM0()    asm volatile("s_waitcnt vmcnt(0)" ::: "memory")
#define SCH0()   __builtin_amdgcn_sched_barrier(0)
#define PRIO(x)  __builtin_amdgcn_s_setprio(x)

__global__ __launch_bounds__(512, 2) void gemm256(const unsigned short* __restrict__ A,
                                                  const unsigned short* __restrict__ B,
                                                  const float* __restrict__ bias,
                                                  float* __restrict__ C) {
    __shared__ __attribute__((aligned(16))) char smem[2][32768];   // A only, 64 KiB
    char* sm = (char*)&smem[0][0];

    const int t = threadIdx.x;
    const int l = t & 63;
    const int w = __builtin_amdgcn_readfirstlane(t >> 6);  // 0..7
    const int wm = w >> 2;        // 0..1  (M half)
    const int wn = w & 3;         // 0..3  (N quarter)

    // bijective XCD swizzle (256 blocks, 8 XCDs)
    int bid = blockIdx.x;
    int swz = (bid & 7) * 32 + (bid >> 3);
    int brow = (swz >> 4) * BM;
    int bcol = (swz & 15) * BN;

    // ---- A staging addresses (pre-swizzled global source, linear LDS dest) ----
    const int lr8  = l >> 3;                 // row in 8-row slab
    const int slot = l & 7;
    const int scol = (slot ^ lr8) << 3;      // swizzled source col (elements)
    const unsigned short* pA = A + (size_t)(brow + w * 8 + lr8) * KDIM + scol;

    // stage one 128-row half of A(kt) into buffer b (2 gld16)
#define STAGE_A(b, h, kt) do {                                                 \
    const unsigned short* _s = pA + (size_t)(h) * 128 * KDIM + (size_t)(kt) * BK; \
    gld16(sm + (b) * 32768 + (h) * 16384 + w * 1024, _s);                      \
    gld16(sm + (b) * 32768 + (h) * 16384 + 8192 + w * 1024,                    \
          _s + (size_t)64 * KDIM);                                             \
} while (0)
#define STAGE4(b, kt) do { STAGE_A(b, 0, kt); STAGE_A(b, 1, kt); } while (0)

    // ---- A fragment read addressing (16x16x32) ----
    const int fr  = l & 15;
    const int fq  = l >> 4;
    const int kx0 = ((fq    ) ^ (fr & 7)) << 4;   // ks=0 swizzled chunk byte
    const int kx1 = ((fq + 4) ^ (fr & 7)) << 4;   // ks=1
    const int frA = fr * 128;

#define RD_A(b, mh) do {                                                        \
    const char* _p = sm + (b) * 32768 + wm * 16384 + (mh) * 8192 + frA;         \
    _Pragma("unroll")                                                           \
    for (int m = 0; m < 4; ++m) {                                               \
        av[m][0] = *(const bf16x8*)(_p + m * 2048 + kx0);                       \
        av[m][1] = *(const bf16x8*)(_p + m * 2048 + kx1);                       \
    }                                                                           \
} while (0)

    // ---- B fragment direct global load (per-wave 64x64 tile) ----
    // B-operand lane map (16x16x32): out-col = fr, k = ks*32 + fq*8 + i
    const unsigned short* pBg = B + (size_t)(bcol + wn * 64 + fr) * KDIM + fq * 8;

#define GLB_B(arr, kt) do {                                                     \
    const unsigned short* _b = pBg + (size_t)(kt) * BK;                         \
    _Pragma("unroll")                                                           \
    for (int nf = 0; nf < 4; ++nf) {                                            \
        arr[nf][0] = *(const bf16x8*)(_b + (size_t)(nf * 16) * KDIM);           \
        arr[nf][1] = *(const bf16x8*)(_b + (size_t)(nf * 16) * KDIM + 32);      \
    }                                                                           \
} while (0)

    // one half (mh) of the per-wave output: 4 m-frags x 4 n-frags x 2 ks
#define MMH(mh, B_)                                                             \
    _Pragma("unroll")                                                           \
    for (int nf = 0; nf < 4; ++nf)                                              \
        _Pragma("unroll")                                                       \
        for (int m = 0; m < 4; ++m)                                             \
            _Pragma("unroll")                                                   \
            for (int ks = 0; ks < 2; ++ks)                                      \
                acc[(mh) * 4 + m][nf] =                                         \
                    __builtin_amdgcn_mfma_f32_16x16x32_bf16(                    \
                        av[m][ks], B_[nf][ks], acc[(mh) * 4 + m][nf], 0, 0, 0);

    f32x4 acc[8][4];
    #pragma unroll
    for (int m = 0; m < 8; ++m)
        #pragma unroll
        for (int n = 0; n < 4; ++n)
            acc[m][n] = f32x4{0.f, 0.f, 0.f, 0.f};

    bf16x8 av[4][2], bEv[4][2], bOd[4][2];

    // ---- prologue: A(0) -> buf0, B(0) -> bEv ----
    STAGE4(0, 0);
    GLB_B(bEv, 0);

    // ---- main loop: 2 K-tiles per iteration (even buf0/bEv, odd buf1/bOd) ----
    for (int it = 0; it < 32; ++it) {
        const int kO  = 2 * it + 1;
        const int kE2 = (2 * it + 2) & 63;   // wraps on last iter (never read)

        // ==== even tile T=2it: buf0, consume bEv ====
        VM0(); BAR(); SCH0();
        RD_A(0, 0);
        GLB_B(bOd, kO);
        STAGE4(1, kO);
        LGKM0(); SCH0();
        PRIO(1); MMH(0, bEv); PRIO(0); SCH0();
        RD_A(0, 1);
        LGKM0(); SCH0();
        PRIO(1); MMH(1, bEv); PRIO(0);

        // ==== odd tile T=2it+1: buf1, consume bOd ====
        VM0(); BAR(); SCH0();
        RD_A(1, 0);
        GLB_B(bEv, kE2);
        STAGE4(0, kE2);
        LGKM0(); SCH0();
        PRIO(1); MMH(0, bOd); PRIO(0); SCH0();
        RD_A(1, 1);
        LGKM0(); SCH0();
        PRIO(1); MMH(1, bOd); PRIO(0);
    }

    // ---- epilogue: C[row][col] = acc + bias[col] ----
    // C/D layout: col = lane&15, row = (lane>>4)*4 + reg
    float bb[4];
    #pragma unroll
    for (int n = 0; n < 4; ++n) bb[n] = bias[bcol + wn * 64 + n * 16 + fr];
    #pragma unroll
    for (int mi = 0; mi < 8; ++mi) {
        #pragma unroll
        for (int q = 0; q < 4; ++q) {
            int row = brow + wm * 128 + mi * 16 + fq * 4 + q;
            float* crow = C + (size_t)row * NDIM + bcol + wn * 64;
            #pragma unroll
            for (int n = 0; n < 4; ++n)
                crow[n * 16 + fr] = acc[mi][n][q] + bb[n];
        }
    }
}

// ---------- launch ----------
extern "C" void kernel_launch(void* const* d_in, const int* in_sizes, int n_in,
                              void* d_out, int out_size, void* d_ws, size_t ws_size,
                              hipStream_t stream) {
    const float* x = (const float*)d_in[0];
    const float* w = (const float*)d_in[1];
    const float* b = (const float*)d_in[2];
    float* out = (float*)d_out;

    unsigned short* xb = (unsigned short*)d_ws;                         // 32 MB
    unsigned short* wq = xb + (size_t)NDIM * KDIM;                      // 32 MB

    prep_kernel<<<32768, 256, 0, stream>>>(x, w, xb, wq);
    gemm256<<<(MDIM / BM) * (NDIM / BN), 512, 0, stream>>>(xb, wq, b, out);
}

// Round 9
// 168.242 us; speedup vs baseline: 2.0380x; 1.3077x over previous
//
#include <hip/hip_runtime.h>
#include <hip/hip_bf16.h>
#include <stdint.h>

#define KDIM 4096
#define NDIM 4096
#define MDIM 4096
#define BM 256
#define BN 256
#define BK 64

typedef __attribute__((ext_vector_type(8))) short bf16x8;
typedef __attribute__((ext_vector_type(4))) float f32x4;

// ---------- helpers ----------

__device__ __forceinline__ unsigned short bf16bits(float f) {
    union { float f; uint32_t u; } c; c.f = f;
    uint32_t u = c.u;
    uint32_t r = (u + 0x7fffu + ((u >> 16) & 1u)) >> 16;   // RNE
    return (unsigned short)r;
}

// Faithful FP4 E2M1 quant-dequant (matches reference float math).
__device__ __forceinline__ float fp4qd(float x) {
    float a = fabsf(x);
    if (a == 0.0f) return 0.0f;
    float e = floorf(log2f(a));
    float val;
    if (e < 0.0f) {                       // subnormal path
        float mant = fminf(fmaxf(rintf(a * 2.0f), 0.0f), 1.0f);
        val = mant * 0.5f;
    } else {
        float ec = fminf(e, 2.0f);
        float p  = exp2f(ec);             // exact: 1,2,4
        float mant = fminf(fmaxf(rintf((a / p - 1.0f) * 2.0f), 0.0f), 1.0f);
        val = (1.0f + 0.5f * mant) * p;
    }
    return (x < 0.0f) ? -val : val;
}

__device__ __forceinline__ void gld16(void* lds, const void* g) {
    __builtin_amdgcn_global_load_lds(
        (const __attribute__((address_space(1))) unsigned int*)g,
        (__attribute__((address_space(3))) unsigned int*)lds,
        16, 0, 0);
}

// ---------- fused prep ----------
// blocks [0,16384): x f32->bf16 (linear).
// blocks [16384,18432): W fp4-qd -> bf16, written in FRAGMENT-MAJOR layout:
//   Wq2[kt][c][inst][lane][16B]  (strides: inst 1KB, c 8KB, kt 512KB)
//   inst = nf + ks*4; lane = (row&15) | (kslot<<4); granule holds
//   B[row][k = kt*64 + ks*32 + kslot*8 .. +8]  with row = c*64 + nf*16 + (row&15).
// Per W-block: 16 rows x 512 k. thread t: row = rb*16 + (t>>4), k = kb*512+(t&15)*32..+32.
// amax group (128 k) = 4 adjacent lanes (t&3 quad) -> shfl_xor 1,2.
__global__ __launch_bounds__(256) void prep_kernel(const float* __restrict__ X,
                                                   const float* __restrict__ W,
                                                   unsigned short* __restrict__ Xb,
                                                   char* __restrict__ Wq2) {
    int bid = blockIdx.x;
    int tid = threadIdx.x;
    if (bid < 16384) {
        size_t i = ((size_t)bid * 256 + tid) * 4;
        float4 v = *(const float4*)(X + i);
        ushort4 o;
        o.x = bf16bits(v.x); o.y = bf16bits(v.y);
        o.z = bf16bits(v.z); o.w = bf16bits(v.w);
        *(ushort4*)(Xb + i) = o;
    } else {
        int bw = bid - 16384;            // [0, 2048)
        int rb = bw >> 3;                // row-block (16 rows)
        int kb = bw & 7;                 // k-block (512 k)
        int row = rb * 16 + (tid >> 4);
        int kq  = tid & 15;
        int k0  = kb * 512 + kq * 32;
        const float* src = W + (size_t)row * KDIM + k0;

        float v[32];
        float am = 0.f;
        #pragma unroll
        for (int j = 0; j < 8; ++j) {
            float4 f = *(const float4*)(src + j * 4);
            v[j*4+0] = f.x; v[j*4+1] = f.y; v[j*4+2] = f.z; v[j*4+3] = f.w;
            am = fmaxf(am, fmaxf(fmaxf(fabsf(f.x), fabsf(f.y)),
                                 fmaxf(fabsf(f.z), fabsf(f.w))));
        }
        am = fmaxf(am, __shfl_xor(am, 1));
        am = fmaxf(am, __shfl_xor(am, 2));          // quad (t&3) = one 128-group
        float scale = (am == 0.0f) ? 1.0f : am / 6.0f;

        const int c   = row >> 6;
        const int nf  = (row >> 4) & 3;
        const int r15 = row & 15;
        #pragma unroll
        for (int g = 0; g < 4; ++g) {
            uint32_t u[4];
            #pragma unroll
            for (int p = 0; p < 4; ++p) {
                float q0 = fp4qd(v[g*8 + p*2    ] / scale) * scale;
                float q1 = fp4qd(v[g*8 + p*2 + 1] / scale) * scale;
                u[p] = (uint32_t)bf16bits(q0) | ((uint32_t)bf16bits(q1) << 16);
            }
            int k8    = (k0 >> 3) + g;
            int kt    = k8 >> 3;
            int kk8   = k8 & 7;
            int ks    = kk8 >> 2;
            int kslot = kk8 & 3;
            size_t addr = ((size_t)((kt * 64 + c) * 8 + nf + ks * 4) << 10)
                        + (size_t)((kslot * 16 + r15) << 4);
            uint4 o = make_uint4(u[0], u[1], u[2], u[3]);
            *(uint4*)(Wq2 + addr) = o;
        }
    }
}

// ---------- GEMM: 256x256 tile, A in LDS, B in registers (fragment-major) --
// 8 waves (2M x 4N), per-wave 128x64, acc[8][4]. LDS = A only, 64 KiB dbuf.
// Per K-tile: 1 x vmcnt(0) + 1 barrier (drain ops issued one full tile ago,
// ~2500 cy slack); 16 A ds_reads (conflict-free chunk-XOR); 8 coalesced
// B dwordx4 (1KB each, fragment-major -> registers, double-buffered bEv/bOd);
// 4 A gld16 stages; two 32-MFMA clusters. LDS port load ~1250cy << MFMA 2483.

#define BAR()    __builtin_amdgcn_s_barrier()
#define LGKM0()  asm volatile("s_waitcnt lgkmcnt(0)" ::: "memory")
#define VM0()    asm volatile("s_waitcnt vmcnt(0)" ::: "memory")
#define SCH0()   __builtin_amdgcn_sched_barrier(0)
#define PRIO(x)  __builtin_amdgcn_s_setprio(x)

__global__ __launch_bounds__(512, 2) void gemm256(const unsigned short* __restrict__ A,
                                                  const char* __restrict__ Bq,
                                                  const float* __restrict__ bias,
                                                  float* __restrict__ C) {
    __shared__ __attribute__((aligned(16))) char smem[2][32768];   // A only
    char* sm = (char*)&smem[0][0];

    const int t = threadIdx.x;
    const int l = t & 63;
    const int w = __builtin_amdgcn_readfirstlane(t >> 6);  // 0..7
    const int wm = w >> 2;        // 0..1  (M half)
    const int wn = w & 3;         // 0..3  (N quarter)

    // bijective XCD swizzle (256 blocks, 8 XCDs)
    int bid = blockIdx.x;
    int swz = (bid & 7) * 32 + (bid >> 3);
    int brow = (swz >> 4) * BM;
    int bcol = (swz & 15) * BN;

    // ---- A staging (pre-swizzled global source, linear LDS dest) ----
    const int lr8  = l >> 3;
    const int slot = l & 7;
    const int scol = (slot ^ lr8) << 3;
    const unsigned short* pA = A + (size_t)(brow + w * 8 + lr8) * KDIM + scol;

#define STAGE_A(b, h, kt) do {                                                 \
    const unsigned short* _s = pA + (size_t)(h) * 128 * KDIM + (size_t)(kt) * BK; \
    gld16(sm + (b) * 32768 + (h) * 16384 + w * 1024, _s);                      \
    gld16(sm + (b) * 32768 + (h) * 16384 + 8192 + w * 1024,                    \
          _s + (size_t)64 * KDIM);                                             \
} while (0)
#define STAGE4(b, kt) do { STAGE_A(b, 0, kt); STAGE_A(b, 1, kt); } while (0)

    // ---- A fragment reads (16x16x32) ----
    const int fr  = l & 15;
    const int fq  = l >> 4;
    const int kx0 = ((fq    ) ^ (fr & 7)) << 4;
    const int kx1 = ((fq + 4) ^ (fr & 7)) << 4;
    const int frA = fr * 128;

#define RD_A(b, mh) do {                                                        \
    const char* _p = sm + (b) * 32768 + wm * 16384 + (mh) * 8192 + frA;         \
    _Pragma("unroll")                                                           \
    for (int m = 0; m < 4; ++m) {                                               \
        av[m][0] = *(const bf16x8*)(_p + m * 2048 + kx0);                       \
        av[m][1] = *(const bf16x8*)(_p + m * 2048 + kx1);                       \
    }                                                                           \
} while (0)

    // ---- B fragment loads: fragment-major, 8 x 1KB contiguous ----
    const char* pBq = Bq + ((size_t)(bcol >> 6) + wn) * 8192 + (size_t)l * 16;

#define GLB_B(arr, kt) do {                                                     \
    const char* _b = pBq + (size_t)(kt) * 524288;                               \
    arr[0][0] = *(const bf16x8*)(_b          );                                 \
    arr[1][0] = *(const bf16x8*)(_b + 1024   );                                 \
    arr[2][0] = *(const bf16x8*)(_b + 2048   );                                 \
    arr[3][0] = *(const bf16x8*)(_b + 3072   );                                 \
    arr[0][1] = *(const bf16x8*)(_b + 4096   );                                 \
    arr[1][1] = *(const bf16x8*)(_b + 5120   );                                 \
    arr[2][1] = *(const bf16x8*)(_b + 6144   );                                 \
    arr[3][1] = *(const bf16x8*)(_b + 7168   );                                 \
} while (0)

#define MMH(mh, B_)                                                             \
    _Pragma("unroll")                                                           \
    for (int m = 0; m < 4; ++m)                                                 \
        _Pragma("unroll")                                                       \
        for (int nf = 0; nf < 4; ++nf)                                          \
            _Pragma("unroll")                                                   \
            for (int ks = 0; ks < 2; ++ks)                                      \
                acc[(mh) * 4 + m][nf] =                                         \
                    __builtin_amdgcn_mfma_f32_16x16x32_bf16(                    \
                        av[m][ks], B_[nf][ks], acc[(mh) * 4 + m][nf], 0, 0, 0);

    f32x4 acc[8][4];
    #pragma unroll
    for (int m = 0; m < 8; ++m)
        #pragma unroll
        for (int n = 0; n < 4; ++n)
            acc[m][n] = f32x4{0.f, 0.f, 0.f, 0.f};

    bf16x8 av[4][2], bEv[4][2], bOd[4][2];

    // ---- prologue: issue tile0 A-stage + B-load; loop-top VM0/BAR drains ----
    GLB_B(bEv, 0);
    STAGE4(0, 0);

    for (int it = 0; it < 32; ++it) {
        const int kO  = 2 * it + 1;
        const int kE2 = (2 * it + 2) & 63;   // wraps on last iter (never read)

        // ==== even tile: buf0 / bEv ====
        VM0(); BAR(); SCH0();
        RD_A(0, 0);
        GLB_B(bOd, kO);
        STAGE4(1, kO);
        LGKM0(); SCH0();
        PRIO(1); MMH(0, bEv); PRIO(0); SCH0();
        RD_A(0, 1);
        LGKM0(); SCH0();
        PRIO(1); MMH(1, bEv); PRIO(0);

        // ==== odd tile: buf1 / bOd ====
        VM0(); BAR(); SCH0();
        RD_A(1, 0);
        GLB_B(bEv, kE2);
        STAGE4(0, kE2);
        LGKM0(); SCH0();
        PRIO(1); MMH(0, bOd); PRIO(0); SCH0();
        RD_A(1, 1);
        LGKM0(); SCH0();
        PRIO(1); MMH(1, bOd); PRIO(0);
    }

    // ---- epilogue: C[row][col] = acc + bias[col] ----
    // C/D layout: col = lane&15, row = (lane>>4)*4 + reg
    float bb[4];
    #pragma unroll
    for (int n = 0; n < 4; ++n) bb[n] = bias[bcol + wn * 64 + n * 16 + fr];
    #pragma unroll
    for (int mi = 0; mi < 8; ++mi) {
        #pragma unroll
        for (int q = 0; q < 4; ++q) {
            int row = brow + wm * 128 + mi * 16 + fq * 4 + q;
            float* crow = C + (size_t)row * NDIM + bcol + wn * 64;
            #pragma unroll
            for (int n = 0; n < 4; ++n)
                crow[n * 16 + fr] = acc[mi][n][q] + bb[n];
        }
    }
}

// ---------- launch ----------
extern "C" void kernel_launch(void* const* d_in, const int* in_sizes, int n_in,
                              void* d_out, int out_size, void* d_ws, size_t ws_size,
                              hipStream_t stream) {
    const float* x = (const float*)d_in[0];
    const float* w = (const float*)d_in[1];
    const float* b = (const float*)d_in[2];
    float* out = (float*)d_out;

    unsigned short* xb = (unsigned short*)d_ws;                         // 32 MB
    char* wq2 = (char*)d_ws + (size_t)NDIM * KDIM * 2;                  // 32 MB

    prep_kernel<<<16384 + 2048, 256, 0, stream>>>(x, w, xb, wq2);
    gemm256<<<(MDIM / BM) * (NDIM / BN), 512, 0, stream>>>(xb, wq2, b, out);
}